// Round 1
// 188.137 us; speedup vs baseline: 1.0362x; 1.0362x over previous
//
#include <hip/hip_runtime.h>
#include <math.h>

#define B_ROWS 2048
#define P_ROWS 100000
#define D_DIM  128
#define NPC    64                 // pool chunks (grid.x of gemm)
#define NT     782                // 128-row pool tiles
#define TILEB  32768              // 128 pool-rows x 128 bf16 (256 B/row)
#define NCAND  (NPC * 3)          // 192 screened candidates per row

typedef short short8 __attribute__((ext_vector_type(8)));
typedef float f32x4  __attribute__((ext_vector_type(4)));
typedef unsigned long long u64;

// bf16 RNE
__device__ __forceinline__ unsigned short f2bf(float f) {
    unsigned u = __float_as_uint(f);
    u += 0x7fffu + ((u >> 16) & 1u);
    return (unsigned short)(u >> 16);
}

__device__ __forceinline__ void async16(const char* g, char* l) {
    __builtin_amdgcn_global_load_lds(
        (const __attribute__((address_space(1))) unsigned int*)g,
        (__attribute__((address_space(3))) unsigned int*)l,
        16, 0, 0);
}

// u64 branchless top-3 insert
__device__ __forceinline__ void kins64(u64 k, u64& t0, u64& t1, u64& t2) {
    u64 m0 = (t0 < k) ? t0 : k;  t0 = (t0 < k) ? k : t0;
    u64 m1 = (t1 < m0) ? t1 : m0; t1 = (t1 < m0) ? m0 : t1;
    t2 = (t2 < m1) ? m1 : t2;
}

// fp64 top-3 insert with index tie-break (lower index wins)
__device__ __forceinline__ void ins3d(double v, int c,
                                      double& v0, int& i0,
                                      double& v1, int& i1,
                                      double& v2, int& i2) {
    bool b0 = (v > v0) || (v == v0 && c < i0);
    bool b1 = (v > v1) || (v == v1 && c < i1);
    bool b2 = (v > v2) || (v == v2 && c < i2);
    if (b0)      { v2 = v1; i2 = i1; v1 = v0; i1 = i0; v0 = v; i0 = c; }
    else if (b1) { v2 = v1; i2 = i1; v1 = v;  i1 = c; }
    else if (b2) { v2 = v;  i2 = c; }
}

// ---------------------------------------------------------------------------
// Kernel 1 (R15 merged): blocks [0,NT) pack pool; blocks [NT,NT+512) pack
// sess. Pool path is SINGLE-PASS: row norm via 4-step shfl_xor inside the
// 16-lane row group (no LDS round-trip, no barrier). One barrier at the end
// for the per-block S partial.
// ---------------------------------------------------------------------------
__global__ void pack_kernel(const float* __restrict__ sess,
                            const float* __restrict__ pool,
                            char* __restrict__ sess2,
                            char* __restrict__ pool2,
                            float* __restrict__ S_part) {
    const int tid = threadIdx.x;
    const int bx  = blockIdx.x;

    if (bx >= NT) {               // ---- sess path: one wave per row ----
        int row  = (bx - NT) * 4 + (tid >> 6);
        int lane = tid & 63;
        float2 v = ((const float2*)(sess + (size_t)row * D_DIM))[lane];
        float s = v.x * v.x + v.y * v.y;
        #pragma unroll
        for (int o = 32; o > 0; o >>= 1) s += __shfl_xor(s, o);
        float inv = 1.0f / sqrtf(s + (float)D_DIM * 1e-6f);
        ushort2 hv;
        hv.x = f2bf(v.x * inv);
        hv.y = f2bf(v.y * inv);
        *(ushort2*)(sess2 + (size_t)row * 256 + lane * 4) = hv;
        return;
    }

    // ---- pool path ----
    __shared__ float red2[16][128];
    const int T  = bx;
    const int c0 = tid >> 4;      // row-in-iteration (16 rows/iter)
    const int g  = tid & 15;      // 8-elem group within the row

    float sacc[8] = {0.f,0.f,0.f,0.f,0.f,0.f,0.f,0.f};
    #pragma unroll
    for (int it = 0; it < 8; ++it) {
        int c = it * 16 + c0;
        int n = T * 128 + c;
        float4 a = make_float4(0.f, 0.f, 0.f, 0.f), b = a;
        if (n < P_ROWS) {
            const float4* src = (const float4*)(pool + (size_t)n * D_DIM + g * 8);
            a = src[0]; b = src[1];
        }
        float s = a.x*a.x + a.y*a.y + a.z*a.z + a.w*a.w
                + b.x*b.x + b.y*b.y + b.z*b.z + b.w*b.w;
        // row-sum across the 16 lanes owning row c (aligned 16-lane group)
        s += __shfl_xor(s, 1);
        s += __shfl_xor(s, 2);
        s += __shfl_xor(s, 4);
        s += __shfl_xor(s, 8);
        float inv = 1.0f / sqrtf(s + (float)D_DIM * 1e-6f);
        const float f[8] = {a.x, a.y, a.z, a.w, b.x, b.y, b.z, b.w};
        short8 hv;
        #pragma unroll
        for (int j = 0; j < 8; ++j) {
            float w = f[j] * inv;
            hv[j] = (short)f2bf(w);
            sacc[j] += w;
        }
        *(short8*)(pool2 + (size_t)T * TILEB + c * 256 + ((g ^ (c & 7)) * 16)) = hv;
    }
    #pragma unroll
    for (int j = 0; j < 8; ++j) red2[c0][g * 8 + j] = sacc[j];
    __syncthreads();
    if (tid < 128) {
        float s = 0.f;
        #pragma unroll
        for (int k = 0; k < 16; ++k) s += red2[k][tid];
        S_part[(size_t)T * 128 + tid] = s;
    }
}

// ---------------------------------------------------------------------------
// Kernel 2: hi-bf16 MFMA cosine SCREEN + fused reduce_S.
// R16 change: per-lane screen keeps TOP-2 (was top-3). The 16-lane merge
// still emits top-3 per (row,pc); a per-lane top-2 can only miss a needed
// candidate if >=3 of a row's per-pc top-3 columns share one lane class
// (P ~ 1e-6 per row). Screen chain is now 3 VALU ops/elem (pack + fmed3 +
// fmax) instead of 4 — the kernel is VALU-bound (61% VALUBusy vs 24%
// MfmaUtil), screen was ~71% of VALU ops.
// NOTE: launch_bounds stays (256,2) — (256,4) spills ~850 MB (R8).
// ---------------------------------------------------------------------------
__launch_bounds__(256, 2)
__global__ void gemm_topk_kernel(const char* __restrict__ sess2,
                                 const char* __restrict__ pool2,
                                 u64* __restrict__ partials,
                                 const float* __restrict__ S_part,
                                 float* __restrict__ S) {
    __shared__ char lds[TILEB];

    const int tid = threadIdx.x;
    const int pc  = blockIdx.x;
    const int mt  = blockIdx.y;

    if (mt == 16) {               // ---- reduce_S path: 64 blocks, 2 dims each
        float* part = (float*)lds;
        #pragma unroll
        for (int d2 = 0; d2 < 2; ++d2) {
            int d = pc * 2 + d2;
            float s = 0.f;
            for (int T = tid; T < NT; T += 256)
                s += S_part[(size_t)T * 128 + d];
            part[tid] = s;
            __syncthreads();
            for (int o = 128; o > 0; o >>= 1) {
                if (tid < o) part[tid] += part[tid + o];
                __syncthreads();
            }
            if (tid == 0) S[d] = part[0];
            __syncthreads();
        }
        return;
    }

    const int w   = tid >> 6;
    const int L   = tid & 63;
    const int q   = L >> 4;
    const int l15 = L & 15;
    const int l7  = L & 7;
    const int rowbase = mt * 128 + w * 32;

    short8 afrag[2][4];
    #pragma unroll
    for (int i = 0; i < 2; ++i)
        #pragma unroll
        for (int ks = 0; ks < 4; ++ks)
            afrag[i][ks] = *(const short8*)(sess2 +
                (size_t)(rowbase + i * 16 + l15) * 256 + (ks * 4 + q) * 16);

    int soks[4];
    #pragma unroll
    for (int ks = 0; ks < 4; ++ks) soks[ks] = ((ks * 4 + q) ^ l7) * 16;
    const char* lbase = lds + l15 * 256;

    float key0[2][4], key1[2][4];
    #pragma unroll
    for (int i = 0; i < 2; ++i)
        #pragma unroll
        for (int r = 0; r < 4; ++r)
            key0[i][r] = key1[i][r] = -1e30f;

    int tloc = 0;
    for (int T = pc; T < NT; T += NPC, ++tloc) {
        __syncthreads();
        const char* tb = pool2 + (size_t)T * TILEB;
        #pragma unroll
        for (int rr = 0; rr < 8; ++rr) {
            int idx = rr * 256 + tid;
            async16(tb + idx * 16, lds + idx * 16);
        }
        __syncthreads();

        #pragma unroll
        for (int qt = 0; qt < 4; ++qt) {
            f32x4 acc[2][2];
            #pragma unroll
            for (int i = 0; i < 2; ++i) {
                acc[i][0] = (f32x4){0.f,0.f,0.f,0.f};
                acc[i][1] = (f32x4){0.f,0.f,0.f,0.f};
            }
            #pragma unroll
            for (int ks = 0; ks < 4; ++ks) {
                const char* cb = lbase + qt * 8192 + soks[ks];
                short8 b0 = *(const short8*)(cb);
                short8 b1 = *(const short8*)(cb + 16 * 256);
                #pragma unroll
                for (int i = 0; i < 2; ++i) {
                    acc[i][0] = __builtin_amdgcn_mfma_f32_16x16x32_bf16(
                        afrag[i][ks], b0, acc[i][0], 0, 0, 0);
                    acc[i][1] = __builtin_amdgcn_mfma_f32_16x16x32_bf16(
                        afrag[i][ks], b1, acc[i][1], 0, 0, 0);
                }
            }
            #pragma unroll
            for (int j = 0; j < 2; ++j) {
                const unsigned pos = (unsigned)(tloc * 8 + qt * 2 + j);
                #pragma unroll
                for (int i = 0; i < 2; ++i)
                    #pragma unroll
                    for (int r = 0; r < 4; ++r) {
                        float v = acc[i][j][r];
                        float kf = __uint_as_float(
                            (__float_as_uint(v) & 0xFFFFFF80u) | pos);
                        // top-2 insert: fmed3 reads OLD key0, then fmax updates
                        key1[i][r] = __builtin_amdgcn_fmed3f(kf, key0[i][r], key1[i][r]);
                        key0[i][r] = fmaxf(key0[i][r], kf);
                    }
            }
        }
    }

    #pragma unroll
    for (int i = 0; i < 2; ++i)
        #pragma unroll
        for (int r = 0; r < 4; ++r) {
            float kk[2] = {key0[i][r], key1[i][r]};
            u64 t0 = 0ull, t1 = 0ull, t2 = 0ull;
            #pragma unroll
            for (int k = 0; k < 2; ++k) {
                unsigned u   = __float_as_uint(kk[k]);
                unsigned pos = u & 127u;
                unsigned vb  = u & 0xFFFFFF80u;
                unsigned mono = (vb & 0x80000000u) ? ~vb : (vb | 0x80000000u);
                unsigned col = (unsigned)((pc + (int)(pos >> 3) * NPC) * 128
                                          + (int)(pos & 7u) * 16 + l15);
                u64 key = ((u64)mono << 32) | (u64)(131071u - col);
                kins64(key, t0, t1, t2);
            }
            #pragma unroll
            for (int m = 1; m < 16; m <<= 1) {
                u64 r0 = __shfl_xor(t0, m);
                u64 r1 = __shfl_xor(t1, m);
                u64 r2 = __shfl_xor(t2, m);
                kins64(r0, t0, t1, t2);
                kins64(r1, t0, t1, t2);
                kins64(r2, t0, t1, t2);
            }
            if (l15 == 0) {
                int row = rowbase + i * 16 + q * 4 + r;
                u64* o = partials + ((size_t)row * NPC + pc) * 3;
                o[0] = t0; o[1] = t1; o[2] = t2;
            }
        }
}

// ---------------------------------------------------------------------------
// Kernel 3: one row per block, zero indexed register arrays (R14).
// ---------------------------------------------------------------------------
__launch_bounds__(256)
__global__ void finalize_kernel(const float* __restrict__ sess,
                                const float* __restrict__ pool,
                                const u64* __restrict__ partials,
                                const float* __restrict__ S,
                                float* __restrict__ out_neighbor,
                                float* __restrict__ out_costopk,
                                float* __restrict__ out_sesstopk) {
    __shared__ u64    keys[NCAND];
    __shared__ u64    top8[8];
    __shared__ double vv[8];
    __shared__ int    ii[8];
    __shared__ double s_na, s_dss;
    __shared__ float  s_w[3];
    __shared__ int    s_i[3];

    const int row = blockIdx.x;
    const int tid = threadIdx.x;
    const int w   = tid >> 6;
    const int L   = tid & 63;

    if (tid < NCAND) keys[tid] = partials[(size_t)row * NCAND + tid];
    if (w == 3) {
        float2 sa = ((const float2*)(sess + (size_t)row * D_DIM))[L];
        double na  = (double)sa.x * sa.x + (double)sa.y * sa.y;
        double dss = (double)sa.x * S[2 * L] + (double)sa.y * S[2 * L + 1];
        #pragma unroll
        for (int o = 32; o > 0; o >>= 1) {
            na  += __shfl_xor(na, o);
            dss += __shfl_xor(dss, o);
        }
        if (L == 0) { s_na = na + (double)D_DIM * 1e-6; s_dss = dss; }
    }
    __syncthreads();

    if (w == 0) {
        for (int k = 0; k < 8; ++k) {
            u64 a0 = keys[L], a1 = keys[L + 64], a2 = keys[L + 128];
            u64 m = a0 > a1 ? a0 : a1;
            m = m > a2 ? m : a2;
            u64 g = m;
            #pragma unroll
            for (int o = 1; o < 64; o <<= 1) {
                u64 r = __shfl_xor(g, o);
                g = (r > g) ? r : g;
            }
            if (m == g && g != 0ull) {
                if (a0 == g)      keys[L] = 0ull;
                else if (a1 == g) keys[L + 64] = 0ull;
                else              keys[L + 128] = 0ull;
            }
            if (L == 0) top8[k] = g;
        }
    }
    __syncthreads();

    {
        float2 sa = ((const float2*)(sess + (size_t)row * D_DIM))[L];
        for (int cc = 0; cc < 2; ++cc) {
            int c = 2 * w + cc;
            int idx = 131071 - (int)(top8[c] & 0x1FFFFull);
            bool ok = idx < P_ROWS;
            float2 pb = ok ? ((const float2*)(pool + (size_t)idx * D_DIM))[L]
                           : make_float2(0.f, 0.f);
            double dot = (double)sa.x * pb.x + (double)sa.y * pb.y;
            double nb  = (double)pb.x * pb.x + (double)pb.y * pb.y;
            #pragma unroll
            for (int o = 32; o > 0; o >>= 1) {
                dot += __shfl_xor(dot, o);
                nb  += __shfl_xor(nb, o);
            }
            if (L == 0) {
                vv[c] = ok ? dot / sqrt(s_na * (nb + (double)D_DIM * 1e-6))
                           : -1e300;
                ii[c] = idx;
            }
        }
    }
    __syncthreads();

    if (tid == 0) {
        double v0 = -1e300, v1 = -1e300, v2 = -1e300;
        int    i0 = 0x7fffffff, i1 = 0x7fffffff, i2 = 0x7fffffff;
        for (int j = 0; j < 8; ++j) ins3d(vv[j], ii[j], v0, i0, v1, i1, v2, i2);
        double z  = (double)P_ROWS + s_dss / sqrt(s_na) + 390.625;
        double c0 = exp(v0) / z, c1 = exp(v1) / z, c2 = exp(v2) / z;
        double e1 = exp(c1 - c0), e2 = exp(c2 - c0);
        double inv = 1.0 / (1.0 + e1 + e2);
        s_w[0] = (float)inv;
        s_w[1] = (float)(e1 * inv);
        s_w[2] = (float)(e2 * inv);
        s_i[0] = i0; s_i[1] = i1; s_i[2] = i2;
    }
    __syncthreads();

    if (tid < D_DIM) {
        float g0 = pool[(size_t)s_i[0] * D_DIM + tid];
        float g1 = pool[(size_t)s_i[1] * D_DIM + tid];
        float g2 = pool[(size_t)s_i[2] * D_DIM + tid];
        out_sesstopk[((size_t)row * 3 + 0) * D_DIM + tid] = g0;
        out_sesstopk[((size_t)row * 3 + 1) * D_DIM + tid] = g1;
        out_sesstopk[((size_t)row * 3 + 2) * D_DIM + tid] = g2;
        out_neighbor[(size_t)row * D_DIM + tid] =
            s_w[0] * g0 + s_w[1] * g1 + s_w[2] * g2;
        if (tid < 3) out_costopk[row * 3 + tid] = s_w[tid];
    }
}

// ---------------------------------------------------------------------------
extern "C" void kernel_launch(void* const* d_in, const int* in_sizes, int n_in,
                              void* d_out, int out_size, void* d_ws, size_t ws_size,
                              hipStream_t stream) {
    const float* sess = (const float*)d_in[0];   // [2048,128]
    const float* pool = (const float*)d_in[1];   // [100000,128]
    float* out = (float*)d_out;
    float* out_neighbor = out;
    float* out_costopk  = out + (size_t)B_ROWS * D_DIM;
    float* out_sesstopk = out_costopk + (size_t)B_ROWS * 3;

    // ws: S(512B) | S_part(400KB) | partials(3.1MB) | sess2(512KB) | pool2(25.6MB)
    float* Svec     = (float*)d_ws;
    float* S_part   = (float*)((char*)d_ws + 512);
    u64*   partials = (u64*)((char*)d_ws + 512 + (size_t)NT * 128 * 4);
    char*  sess2    = (char*)partials + (size_t)B_ROWS * NCAND * 8;
    char*  pool2    = sess2 + (size_t)B_ROWS * 256;

    pack_kernel<<<NT + 512, 256, 0, stream>>>(sess, pool, sess2, pool2, S_part);

    dim3 g3(NPC, 17);
    gemm_topk_kernel<<<g3, 256, 0, stream>>>(sess2, pool2, partials, S_part, Svec);

    finalize_kernel<<<B_ROWS, 256, 0, stream>>>(
        sess, pool, partials, Svec, out_neighbor, out_costopk, out_sesstopk);
}

// Round 2
// 184.680 us; speedup vs baseline: 1.0556x; 1.0187x over previous
//
#include <hip/hip_runtime.h>
#include <math.h>

#define B_ROWS 2048
#define P_ROWS 100000
#define D_DIM  128
#define NPC    64                 // pool chunks (grid.x of gemm)
#define NT     782                // 128-row pool tiles
#define TILEB  32768              // 128 pool-rows x 128 bf16 (256 B/row)
#define NCAND  (NPC * 3)          // 192 screened candidates (pairs) per row

typedef short short8 __attribute__((ext_vector_type(8)));
typedef float f32x4  __attribute__((ext_vector_type(4)));
typedef unsigned long long u64;

// bf16 RNE
__device__ __forceinline__ unsigned short f2bf(float f) {
    unsigned u = __float_as_uint(f);
    u += 0x7fffu + ((u >> 16) & 1u);
    return (unsigned short)(u >> 16);
}

__device__ __forceinline__ void async16(const char* g, char* l) {
    __builtin_amdgcn_global_load_lds(
        (const __attribute__((address_space(1))) unsigned int*)g,
        (__attribute__((address_space(3))) unsigned int*)l,
        16, 0, 0);
}

// u64 branchless top-3 insert
__device__ __forceinline__ void kins64(u64 k, u64& t0, u64& t1, u64& t2) {
    u64 m0 = (t0 < k) ? t0 : k;  t0 = (t0 < k) ? k : t0;
    u64 m1 = (t1 < m0) ? t1 : m0; t1 = (t1 < m0) ? m0 : t1;
    t2 = (t2 < m1) ? m1 : t2;
}

// fp64 top-3 insert with index tie-break (lower index wins)
__device__ __forceinline__ void ins3d(double v, int c,
                                      double& v0, int& i0,
                                      double& v1, int& i1,
                                      double& v2, int& i2) {
    bool b0 = (v > v0) || (v == v0 && c < i0);
    bool b1 = (v > v1) || (v == v1 && c < i1);
    bool b2 = (v > v2) || (v == v2 && c < i2);
    if (b0)      { v2 = v1; i2 = i1; v1 = v0; i1 = i0; v0 = v; i0 = c; }
    else if (b1) { v2 = v1; i2 = i1; v1 = v;  i1 = c; }
    else if (b2) { v2 = v;  i2 = c; }
}

// ---------------------------------------------------------------------------
// Kernel 1 (R15 merged): blocks [0,NT) pack pool; blocks [NT,NT+512) pack
// sess. Pool path is SINGLE-PASS: row norm via 4-step shfl_xor inside the
// 16-lane row group. One barrier at the end for the per-block S partial.
// ---------------------------------------------------------------------------
__global__ void pack_kernel(const float* __restrict__ sess,
                            const float* __restrict__ pool,
                            char* __restrict__ sess2,
                            char* __restrict__ pool2,
                            float* __restrict__ S_part) {
    const int tid = threadIdx.x;
    const int bx  = blockIdx.x;

    if (bx >= NT) {               // ---- sess path: one wave per row ----
        int row  = (bx - NT) * 4 + (tid >> 6);
        int lane = tid & 63;
        float2 v = ((const float2*)(sess + (size_t)row * D_DIM))[lane];
        float s = v.x * v.x + v.y * v.y;
        #pragma unroll
        for (int o = 32; o > 0; o >>= 1) s += __shfl_xor(s, o);
        float inv = 1.0f / sqrtf(s + (float)D_DIM * 1e-6f);
        ushort2 hv;
        hv.x = f2bf(v.x * inv);
        hv.y = f2bf(v.y * inv);
        *(ushort2*)(sess2 + (size_t)row * 256 + lane * 4) = hv;
        return;
    }

    // ---- pool path ----
    __shared__ float red2[16][128];
    const int T  = bx;
    const int c0 = tid >> 4;      // row-in-iteration (16 rows/iter)
    const int g  = tid & 15;      // 8-elem group within the row

    float sacc[8] = {0.f,0.f,0.f,0.f,0.f,0.f,0.f,0.f};
    #pragma unroll
    for (int it = 0; it < 8; ++it) {
        int c = it * 16 + c0;
        int n = T * 128 + c;
        float4 a = make_float4(0.f, 0.f, 0.f, 0.f), b = a;
        if (n < P_ROWS) {
            const float4* src = (const float4*)(pool + (size_t)n * D_DIM + g * 8);
            a = src[0]; b = src[1];
        }
        float s = a.x*a.x + a.y*a.y + a.z*a.z + a.w*a.w
                + b.x*b.x + b.y*b.y + b.z*b.z + b.w*b.w;
        // row-sum across the 16 lanes owning row c (aligned 16-lane group)
        s += __shfl_xor(s, 1);
        s += __shfl_xor(s, 2);
        s += __shfl_xor(s, 4);
        s += __shfl_xor(s, 8);
        float inv = 1.0f / sqrtf(s + (float)D_DIM * 1e-6f);
        const float f[8] = {a.x, a.y, a.z, a.w, b.x, b.y, b.z, b.w};
        short8 hv;
        #pragma unroll
        for (int j = 0; j < 8; ++j) {
            float w = f[j] * inv;
            hv[j] = (short)f2bf(w);
            sacc[j] += w;
        }
        *(short8*)(pool2 + (size_t)T * TILEB + c * 256 + ((g ^ (c & 7)) * 16)) = hv;
    }
    #pragma unroll
    for (int j = 0; j < 8; ++j) red2[c0][g * 8 + j] = sacc[j];
    __syncthreads();
    if (tid < 128) {
        float s = 0.f;
        #pragma unroll
        for (int k = 0; k < 16; ++k) s += red2[k][tid];
        S_part[(size_t)T * 128 + tid] = s;
    }
}

// ---------------------------------------------------------------------------
// Kernel 2: hi-bf16 MFMA cosine SCREEN + fused reduce_S.
// R17 changes (kernel is VALU-bound: 55% VALUBusy vs 26% MfmaUtil):
//  (a) zero-C MFMA: the first K-slice feeds a persistent zero f32x4 as the
//      C operand, killing 32 acc-init movs per qt (128 VALU ops/tile).
//  (b) PAIR screen: columns j=0/j=1 (16 apart) are max-merged BEFORE the
//      top-2 insert -> 4 VALU ops per 2 elements (was 3/elem). A pair's key
//      is the max of its two columns, so coverage is >= R16's: top-3 columns
//      lie inside top-3 pairs, and finalize exact-rescores BOTH columns of
//      each surviving pair. pos is now 6 bits (tloc*4+qt) -> 26 value bits.
// NOTE: launch_bounds stays (256,2) — (256,4) spills ~850 MB (R8).
// ---------------------------------------------------------------------------
__launch_bounds__(256, 2)
__global__ void gemm_topk_kernel(const char* __restrict__ sess2,
                                 const char* __restrict__ pool2,
                                 u64* __restrict__ partials,
                                 const float* __restrict__ S_part,
                                 float* __restrict__ S) {
    __shared__ char lds[TILEB];

    const int tid = threadIdx.x;
    const int pc  = blockIdx.x;
    const int mt  = blockIdx.y;

    if (mt == 16) {               // ---- reduce_S path: 64 blocks, 2 dims each
        float* part = (float*)lds;
        #pragma unroll
        for (int d2 = 0; d2 < 2; ++d2) {
            int d = pc * 2 + d2;
            float s = 0.f;
            for (int T = tid; T < NT; T += 256)
                s += S_part[(size_t)T * 128 + d];
            part[tid] = s;
            __syncthreads();
            for (int o = 128; o > 0; o >>= 1) {
                if (tid < o) part[tid] += part[tid + o];
                __syncthreads();
            }
            if (tid == 0) S[d] = part[0];
            __syncthreads();
        }
        return;
    }

    const int w   = tid >> 6;
    const int L   = tid & 63;
    const int q   = L >> 4;
    const int l15 = L & 15;
    const int l7  = L & 7;
    const int rowbase = mt * 128 + w * 32;

    short8 afrag[2][4];
    #pragma unroll
    for (int i = 0; i < 2; ++i)
        #pragma unroll
        for (int ks = 0; ks < 4; ++ks)
            afrag[i][ks] = *(const short8*)(sess2 +
                (size_t)(rowbase + i * 16 + l15) * 256 + (ks * 4 + q) * 16);

    int soks[4];
    #pragma unroll
    for (int ks = 0; ks < 4; ++ks) soks[ks] = ((ks * 4 + q) ^ l7) * 16;
    const char* lbase = lds + l15 * 256;

    const f32x4 fz = {0.f, 0.f, 0.f, 0.f};   // persistent zero C-operand

    float key0[2][4], key1[2][4];
    #pragma unroll
    for (int i = 0; i < 2; ++i)
        #pragma unroll
        for (int r = 0; r < 4; ++r)
            key0[i][r] = key1[i][r] = -1e30f;

    int tloc = 0;
    for (int T = pc; T < NT; T += NPC, ++tloc) {
        __syncthreads();
        const char* tb = pool2 + (size_t)T * TILEB;
        #pragma unroll
        for (int rr = 0; rr < 8; ++rr) {
            int idx = rr * 256 + tid;
            async16(tb + idx * 16, lds + idx * 16);
        }
        __syncthreads();

        #pragma unroll
        for (int qt = 0; qt < 4; ++qt) {
            f32x4 acc[2][2];
            {   // ks = 0: C = zero register (no acc init movs)
                const char* cb = lbase + qt * 8192 + soks[0];
                short8 b0 = *(const short8*)(cb);
                short8 b1 = *(const short8*)(cb + 16 * 256);
                #pragma unroll
                for (int i = 0; i < 2; ++i) {
                    acc[i][0] = __builtin_amdgcn_mfma_f32_16x16x32_bf16(
                        afrag[i][0], b0, fz, 0, 0, 0);
                    acc[i][1] = __builtin_amdgcn_mfma_f32_16x16x32_bf16(
                        afrag[i][0], b1, fz, 0, 0, 0);
                }
            }
            #pragma unroll
            for (int ks = 1; ks < 4; ++ks) {
                const char* cb = lbase + qt * 8192 + soks[ks];
                short8 b0 = *(const short8*)(cb);
                short8 b1 = *(const short8*)(cb + 16 * 256);
                #pragma unroll
                for (int i = 0; i < 2; ++i) {
                    acc[i][0] = __builtin_amdgcn_mfma_f32_16x16x32_bf16(
                        afrag[i][ks], b0, acc[i][0], 0, 0, 0);
                    acc[i][1] = __builtin_amdgcn_mfma_f32_16x16x32_bf16(
                        afrag[i][ks], b1, acc[i][1], 0, 0, 0);
                }
            }
            // pair screen: merge j=0/j=1 (cols 16 apart), top-2 insert
            const unsigned ppos = (unsigned)(tloc * 4 + qt);   // 6 bits
            #pragma unroll
            for (int i = 0; i < 2; ++i)
                #pragma unroll
                for (int r = 0; r < 4; ++r) {
                    float v  = fmaxf(acc[i][0][r], acc[i][1][r]);
                    float kf = __uint_as_float(
                        (__float_as_uint(v) & 0xFFFFFFC0u) | ppos);
                    float o0 = key0[i][r];
                    key1[i][r] = __builtin_amdgcn_fmed3f(kf, o0, key1[i][r]);
                    key0[i][r] = fmaxf(o0, kf);
                }
        }
    }

    #pragma unroll
    for (int i = 0; i < 2; ++i)
        #pragma unroll
        for (int r = 0; r < 4; ++r) {
            float kk[2] = {key0[i][r], key1[i][r]};
            u64 t0 = 0ull, t1 = 0ull, t2 = 0ull;
            #pragma unroll
            for (int k = 0; k < 2; ++k) {
                unsigned u   = __float_as_uint(kk[k]);
                unsigned pos = u & 63u;                 // tloc*4 + qt
                unsigned vb  = u & 0xFFFFFFC0u;
                unsigned mono = (vb & 0x80000000u) ? ~vb : (vb | 0x80000000u);
                // col of the j=0 member of the pair; partner is col+16
                unsigned col = (unsigned)((pc + (int)(pos >> 2) * NPC) * 128
                                          + (int)(pos & 3u) * 32 + l15);
                u64 key = ((u64)mono << 32) | (u64)(131071u - col);
                kins64(key, t0, t1, t2);
            }
            #pragma unroll
            for (int m = 1; m < 16; m <<= 1) {
                u64 r0 = __shfl_xor(t0, m);
                u64 r1 = __shfl_xor(t1, m);
                u64 r2 = __shfl_xor(t2, m);
                kins64(r0, t0, t1, t2);
                kins64(r1, t0, t1, t2);
                kins64(r2, t0, t1, t2);
            }
            if (l15 == 0) {
                int row = rowbase + i * 16 + q * 4 + r;
                u64* o = partials + ((size_t)row * NPC + pc) * 3;
                o[0] = t0; o[1] = t1; o[2] = t2;
            }
        }
}

// ---------------------------------------------------------------------------
// Kernel 3: one row per block. R17: top-8 keys are PAIRS -> rescore both
// columns of each pair (16 candidates) using half-wave (32-lane) reductions,
// so the global-fetch round count per wave is unchanged (2).
// ---------------------------------------------------------------------------
__launch_bounds__(256)
__global__ void finalize_kernel(const float* __restrict__ sess,
                                const float* __restrict__ pool,
                                const u64* __restrict__ partials,
                                const float* __restrict__ S,
                                float* __restrict__ out_neighbor,
                                float* __restrict__ out_costopk,
                                float* __restrict__ out_sesstopk) {
    __shared__ u64    keys[NCAND];
    __shared__ u64    top8[8];
    __shared__ double vv[16];
    __shared__ int    ii[16];
    __shared__ double s_na, s_dss;
    __shared__ float  s_w[3];
    __shared__ int    s_i[3];

    const int row = blockIdx.x;
    const int tid = threadIdx.x;
    const int w   = tid >> 6;
    const int L   = tid & 63;

    if (tid < NCAND) keys[tid] = partials[(size_t)row * NCAND + tid];
    if (w == 3) {
        float2 sa = ((const float2*)(sess + (size_t)row * D_DIM))[L];
        double na  = (double)sa.x * sa.x + (double)sa.y * sa.y;
        double dss = (double)sa.x * S[2 * L] + (double)sa.y * S[2 * L + 1];
        #pragma unroll
        for (int o = 32; o > 0; o >>= 1) {
            na  += __shfl_xor(na, o);
            dss += __shfl_xor(dss, o);
        }
        if (L == 0) { s_na = na + (double)D_DIM * 1e-6; s_dss = dss; }
    }
    __syncthreads();

    if (w == 0) {
        for (int k = 0; k < 8; ++k) {
            u64 a0 = keys[L], a1 = keys[L + 64], a2 = keys[L + 128];
            u64 m = a0 > a1 ? a0 : a1;
            m = m > a2 ? m : a2;
            u64 g = m;
            #pragma unroll
            for (int o = 1; o < 64; o <<= 1) {
                u64 r = __shfl_xor(g, o);
                g = (r > g) ? r : g;
            }
            if (m == g && g != 0ull) {
                if (a0 == g)      keys[L] = 0ull;
                else if (a1 == g) keys[L + 64] = 0ull;
                else              keys[L + 128] = 0ull;
            }
            if (L == 0) top8[k] = g;
        }
    }
    __syncthreads();

    {   // rescore: pair c -> columns base (h=0) and base+16 (h=1)
        const int h   = L >> 5;
        const int l31 = L & 31;
        float4 sa = ((const float4*)(sess + (size_t)row * D_DIM))[l31];
        #pragma unroll
        for (int cc = 0; cc < 2; ++cc) {
            int c = 2 * w + cc;
            int base = 131071 - (int)(top8[c] & 0x1FFFFull);
            int idx  = base + h * 16;
            bool ok  = (unsigned)idx < (unsigned)P_ROWS;
            float4 pb = ok ? ((const float4*)(pool + (size_t)idx * D_DIM))[l31]
                           : make_float4(0.f, 0.f, 0.f, 0.f);
            double dot = (double)sa.x * pb.x + (double)sa.y * pb.y
                       + (double)sa.z * pb.z + (double)sa.w * pb.w;
            double nb  = (double)pb.x * pb.x + (double)pb.y * pb.y
                       + (double)pb.z * pb.z + (double)pb.w * pb.w;
            #pragma unroll
            for (int o = 16; o > 0; o >>= 1) {
                dot += __shfl_xor(dot, o);
                nb  += __shfl_xor(nb, o);
            }
            if (l31 == 0) {
                vv[c * 2 + h] = ok ? dot / sqrt(s_na * (nb + (double)D_DIM * 1e-6))
                                   : -1e300;
                ii[c * 2 + h] = idx;
            }
        }
    }
    __syncthreads();

    if (tid == 0) {
        double v0 = -1e300, v1 = -1e300, v2 = -1e300;
        int    i0 = 0x7fffffff, i1 = 0x7fffffff, i2 = 0x7fffffff;
        for (int j = 0; j < 16; ++j) ins3d(vv[j], ii[j], v0, i0, v1, i1, v2, i2);
        double z  = (double)P_ROWS + s_dss / sqrt(s_na) + 390.625;
        double c0 = exp(v0) / z, c1 = exp(v1) / z, c2 = exp(v2) / z;
        double e1 = exp(c1 - c0), e2 = exp(c2 - c0);
        double inv = 1.0 / (1.0 + e1 + e2);
        s_w[0] = (float)inv;
        s_w[1] = (float)(e1 * inv);
        s_w[2] = (float)(e2 * inv);
        s_i[0] = i0; s_i[1] = i1; s_i[2] = i2;
    }
    __syncthreads();

    if (tid < D_DIM) {
        float g0 = pool[(size_t)s_i[0] * D_DIM + tid];
        float g1 = pool[(size_t)s_i[1] * D_DIM + tid];
        float g2 = pool[(size_t)s_i[2] * D_DIM + tid];
        out_sesstopk[((size_t)row * 3 + 0) * D_DIM + tid] = g0;
        out_sesstopk[((size_t)row * 3 + 1) * D_DIM + tid] = g1;
        out_sesstopk[((size_t)row * 3 + 2) * D_DIM + tid] = g2;
        out_neighbor[(size_t)row * D_DIM + tid] =
            s_w[0] * g0 + s_w[1] * g1 + s_w[2] * g2;
        if (tid < 3) out_costopk[row * 3 + tid] = s_w[tid];
    }
}

// ---------------------------------------------------------------------------
extern "C" void kernel_launch(void* const* d_in, const int* in_sizes, int n_in,
                              void* d_out, int out_size, void* d_ws, size_t ws_size,
                              hipStream_t stream) {
    const float* sess = (const float*)d_in[0];   // [2048,128]
    const float* pool = (const float*)d_in[1];   // [100000,128]
    float* out = (float*)d_out;
    float* out_neighbor = out;
    float* out_costopk  = out + (size_t)B_ROWS * D_DIM;
    float* out_sesstopk = out_costopk + (size_t)B_ROWS * 3;

    // ws: S(512B) | S_part(400KB) | partials(3.1MB) | sess2(512KB) | pool2(25.6MB)
    float* Svec     = (float*)d_ws;
    float* S_part   = (float*)((char*)d_ws + 512);
    u64*   partials = (u64*)((char*)d_ws + 512 + (size_t)NT * 128 * 4);
    char*  sess2    = (char*)partials + (size_t)B_ROWS * NCAND * 8;
    char*  pool2    = sess2 + (size_t)B_ROWS * 256;

    pack_kernel<<<NT + 512, 256, 0, stream>>>(sess, pool, sess2, pool2, S_part);

    dim3 g3(NPC, 17);
    gemm_topk_kernel<<<g3, 256, 0, stream>>>(sess2, pool2, partials, S_part, Svec);

    finalize_kernel<<<B_ROWS, 256, 0, stream>>>(
        sess, pool, partials, Svec, out_neighbor, out_costopk, out_sesstopk);
}